// Round 13
// baseline (113.717 us; speedup 1.0000x reference)
//
#include <hip/hip_runtime.h>

#define B_ 8
#define L_ 4096
#define D_ 512
#define M_ 64

typedef __attribute__((ext_vector_type(8))) short bh8;
typedef __attribute__((ext_vector_type(4))) float f4;
typedef __attribute__((ext_vector_type(4))) unsigned u32x4;

__device__ inline unsigned short f2bf(float f) {
  unsigned u = __float_as_uint(f);
  return (unsigned short)((u + 0x7fffu + ((u >> 16) & 1u)) >> 16);
}
__device__ inline unsigned packbf(float lo, float hi) {
  return (unsigned)f2bf(lo) | ((unsigned)f2bf(hi) << 16);
}

// ---------------- forward-DFT coefficient matrix (bf16), PLAIN row-major [r][l]
__global__ void k_ftab(unsigned short* __restrict__ F) {
  int t = blockIdx.x * 256 + threadIdx.x;  // 128*4096
  int r = t >> 12, l = t & 4095;
  int k = r & 63, part = r >> 6;
  int ph = (k * l) & (L_ - 1);
  double ang = 6.283185307179586476925286766559 * (double)ph / (double)L_;
  float v = part ? (float)(-sin(ang)) : (float)(cos(ang));
  F[t] = f2bf(v);
}

// ----------------------------------------- inverse-DFT coefficient matrix (bf16)
__global__ void k_gtab(unsigned short* __restrict__ G) {
  int t = blockIdx.x * 256 + threadIdx.x;  // L_*128
  int l = t >> 7, j = t & 127;
  int k = j & 63, part = j >> 6;
  int ph = (k * l) & (L_ - 1);
  double ang = 6.283185307179586476925286766559 * (double)ph / (double)L_;
  double ck = (k == 0 ? 1.0 : 2.0) / (double)L_;
  float v = part ? (float)(-ck * sin(ang)) : (float)(ck * cos(ang));
  G[t] = f2bf(v);
}

// ------------------------- stage 1: Qft = F(128x4096) * q[b](4096x512) via MFMA
__global__ __launch_bounds__(512, 4) void k_dft_mfma(
    const float* __restrict__ q, const unsigned short* __restrict__ F,
    float* __restrict__ pQ) {
  int tid = threadIdx.x;
  int dt = blockIdx.x, b = blockIdx.y, kc = blockIdx.z;
  int d0 = dt * 64;
  int lbase = kc * 512;

  int w = tid >> 6, lane = tid & 63;
  int mh = w & 3, nc = w >> 2;
  int lr = lane & 15, kg = lane >> 4;

  f4 acc[2][2];
#pragma unroll
  for (int i = 0; i < 2; ++i)
#pragma unroll
    for (int j = 0; j < 2; ++j) { f4 z = {0.f, 0.f, 0.f, 0.f}; acc[i][j] = z; }

  const unsigned short* A0 = F + (size_t)(mh * 32 + lr) * 4096 + lbase + kg * 8;
  const unsigned short* A1 = A0 + (size_t)16 * 4096;
  const float* q0 = q + ((size_t)b * L_ + lbase + kg * 8) * D_ + d0 + nc * 32 + lr;

#pragma unroll 2
  for (int s = 0; s < 16; ++s) {
    const float* qs = q0 + (size_t)s * 32 * D_;
    float v0[8], v1[8];
#pragma unroll
    for (int j = 0; j < 8; ++j) {
      v0[j] = qs[(size_t)j * D_];
      v1[j] = qs[(size_t)j * D_ + 16];
    }
    union { u32x4 u; bh8 h; } bf0, bf1;
    bf0.u.x = packbf(v0[0], v0[1]); bf0.u.y = packbf(v0[2], v0[3]);
    bf0.u.z = packbf(v0[4], v0[5]); bf0.u.w = packbf(v0[6], v0[7]);
    bf1.u.x = packbf(v1[0], v1[1]); bf1.u.y = packbf(v1[2], v1[3]);
    bf1.u.z = packbf(v1[4], v1[5]); bf1.u.w = packbf(v1[6], v1[7]);
    bh8 af0 = *(const bh8*)(A0 + s * 32);
    bh8 af1 = *(const bh8*)(A1 + s * 32);
    acc[0][0] = __builtin_amdgcn_mfma_f32_16x16x32_bf16(af0, bf0.h, acc[0][0], 0, 0, 0);
    acc[0][1] = __builtin_amdgcn_mfma_f32_16x16x32_bf16(af0, bf1.h, acc[0][1], 0, 0, 0);
    acc[1][0] = __builtin_amdgcn_mfma_f32_16x16x32_bf16(af1, bf0.h, acc[1][0], 0, 0, 0);
    acc[1][1] = __builtin_amdgcn_mfma_f32_16x16x32_bf16(af1, bf1.h, acc[1][1], 0, 0, 0);
  }

#pragma unroll
  for (int mi = 0; mi < 2; ++mi) {
    int r = mh * 32 + mi * 16 + kg * 4;
#pragma unroll
    for (int ni = 0; ni < 2; ++ni) {
      int d = d0 + nc * 32 + ni * 16 + lr;
#pragma unroll
      for (int j = 0; j < 4; ++j)
        pQ[(((size_t)kc * 128 + (r + j)) * 8 + b) * 512 + d] = acc[mi][ni][j];
    }
  }
}

// -------------- reduce kc chunks + pack bf16 Qbf[k][b][d]: word = (Qr, Qi)
__global__ __launch_bounds__(256) void k_red2(const float* __restrict__ pQ,
                                              unsigned* __restrict__ Qbf) {
  int g = blockIdx.x * 256 + threadIdx.x;  // 64*8*128 = 65536
  int dq = g & 127;
  int b = (g >> 7) & 7;
  int k = g >> 10;
  f4 sr = {0.f, 0.f, 0.f, 0.f}, si = {0.f, 0.f, 0.f, 0.f};
#pragma unroll
  for (int kc = 0; kc < 8; ++kc) {
    size_t base = (((size_t)kc * 128 + k) * 8 + b) * 512 + dq * 4;
    sr += *(const f4*)(pQ + base);
    si += *(const f4*)(pQ + base + (size_t)64 * 8 * 512);
  }
  u32x4 o;
  o.x = packbf(sr[0], si[0]); o.y = packbf(sr[1], si[1]);
  o.z = packbf(sr[2], si[2]); o.w = packbf(sr[3], si[3]);
  *(u32x4*)(Qbf + ((size_t)k * 8 + b) * 512 + dq * 4) = o;
}

// ------------------------- stage 2 v8: small-block oversubscribed mode-mix
// grid (32 et, 16 dc, 4 kq) = 2048 blocks x 256 thr (4 waves) -> ~5 blocks/CU,
// small barrier domains, dynamic balance. Per block: 32d x 16e x 16k, 64 KB W.
// LDS = one 16 KB Wt; 2 rounds of 16 d; plain loads, TLP hides latency.
__global__ __launch_bounds__(256, 5) void k_mix_mfma(
    const float* __restrict__ wr_, const float* __restrict__ wi_,
    const unsigned* __restrict__ Qbf, float* __restrict__ pOut) {
  __shared__ unsigned Wt[4096];  // 16 KB: [kl16][e16][dp16] packed (Wr,Wi)

  int tid = threadIdx.x;
  int et = blockIdx.x, dc = blockIdx.y, kq = blockIdx.z;
  int e0 = et * 16, D0 = dc * 32, k0 = kq * 16;
  int w = tid >> 6, lane = tid & 63;
  int er = lane & 15, kg = lane >> 4;
  int part = er >> 3, b = er & 7;

  // staging roles: thread -> (e, k-chunk, d-group)
  int se = tid & 15;
  int sk4 = (tid >> 4) & 3;
  int sdg = tid >> 6;

  f4 acc[4];
#pragma unroll
  for (int t = 0; t < 4; ++t) { f4 z = {0.f, 0.f, 0.f, 0.f}; acc[t] = z; }

#pragma unroll 1
  for (int r = 0; r < 2; ++r) {
    if (r) __syncthreads();  // all waves done reading Wt round r-1
    // ---- load + pack 16 d (each thread 4 d)
#pragma unroll
    for (int i = 0; i < 4; ++i) {
      int dl = sdg * 4 + i;                       // 0..15
      size_t dd = (size_t)(D0 + r * 16 + dl);
      size_t gb = (dd * 512 + e0 + se) * 64 + k0 + sk4 * 4;
      float4 vr = *(const float4*)(wr_ + gb);
      float4 vi = *(const float4*)(wi_ + gb);
      int dp = dl ^ (sk4 << 2);
      unsigned* o = &Wt[(sk4 * 4) * 256 + se * 16 + dp];
      o[0]   = packbf(vr.x, vi.x);
      o[256] = packbf(vr.y, vi.y);
      o[512] = packbf(vr.z, vi.z);
      o[768] = packbf(vr.w, vi.w);
    }
    __syncthreads();
    // ---- compute: wave w -> kl = w*4 .. w*4+3, one MFMA each
#pragma unroll
    for (int t = 0; t < 4; ++t) {
      int kl = w * 4 + t;
      int sw = (kl >> 2) << 2;
      union { u32x4 u; bh8 h; } av, bv;
      av.u = *(const u32x4*)&Wt[kl * 256 + er * 16 + ((kg * 4) ^ sw)];
      u32x4 qv = *(const u32x4*)(Qbf +
          ((size_t)(k0 + kl) * 8 + b) * 512 + D0 + r * 16 + kg * 4);
      if (part == 0) {
        bv.u.x = qv.x ^ 0x80000000u; bv.u.y = qv.y ^ 0x80000000u;
        bv.u.z = qv.z ^ 0x80000000u; bv.u.w = qv.w ^ 0x80000000u;
      } else {
        bv.u.x = (qv.x >> 16) | (qv.x << 16); bv.u.y = (qv.y >> 16) | (qv.y << 16);
        bv.u.z = (qv.z >> 16) | (qv.z << 16); bv.u.w = (qv.w >> 16) | (qv.w << 16);
      }
      acc[t] = __builtin_amdgcn_mfma_f32_16x16x32_bf16(av.h, bv.h, acc[t], 0, 0, 0);
    }
  }

  // epilogue: pOut[dc][k*2+part][b][e512]
#pragma unroll
  for (int t = 0; t < 4; ++t) {
    int kglob = k0 + w * 4 + t;
    size_t off = (size_t)dc * 524288 +
                 (((size_t)kglob * 2 + part) * 8 + b) * 512 + e0 + kg * 4;
    *(f4*)(pOut + off) = acc[t];
  }
}

// ------------- reduce pOut over 16 dc + transpose to bf16 P[b][e][part*64+k]
__global__ __launch_bounds__(256) void k_psum2(const float* __restrict__ pOut,
                                               unsigned* __restrict__ Pw) {
  __shared__ float sP[128 * 33];
  int tid = threadIdx.x;
  int e0 = blockIdx.x * 32, b = blockIdx.y;
  {
    int e = tid & 31, kg4 = tid >> 5;
#pragma unroll
    for (int ii = 0; ii < 16; ++ii) {
      int col = kg4 * 16 + ii;
      int rkp = ((col & 63) << 1) | (col >> 6);
      float s = 0.f;
#pragma unroll
      for (int c = 0; c < 16; ++c)
        s += pOut[(size_t)c * 524288 + (size_t)rkp * 4096 + b * 512 + e0 + e];
      sP[col * 33 + e] = s;
    }
  }
  __syncthreads();
  {
    int e = tid >> 3, c = tid & 7;
    size_t wbase = (((size_t)b * 512 + e0 + e) * 128 + c * 16) >> 1;
#pragma unroll
    for (int ii = 0; ii < 8; ++ii) {
      int col = c * 16 + ii * 2;
      Pw[wbase + ii] = packbf(sP[col * 33 + e], sP[(col + 1) * 33 + e]);
    }
  }
}

// ------------------------- stage 3: y[b] = G(4096x128) * P[b](512x128)^T via MFMA
#define LST 72
__global__ __launch_bounds__(256, 2) void k_inv_mfma(
    const short* __restrict__ G, const short* __restrict__ P,
    float* __restrict__ y) {
  __shared__ short lds[2 * 128 * LST];
  short* As = lds;
  short* Bs = lds + 128 * LST;

  int tid = threadIdx.x;
  int lt = blockIdx.x, et = blockIdx.y, b = blockIdx.z;
  int l0 = lt * 128, e0 = et * 128;

  int wv = tid >> 6, lane = tid & 63;
  int wrow = wv >> 1, wcol = wv & 1;
  int lr = lane & 15, kg = lane >> 4;

  const short* Gb = G + (size_t)l0 * 128;
  const short* Pb = P + (size_t)b * D_ * 128 + (size_t)e0 * 128;

  f4 acc[4][4];
#pragma unroll
  for (int mi = 0; mi < 4; ++mi)
#pragma unroll
    for (int ni = 0; ni < 4; ++ni) {
      f4 z = {0.f, 0.f, 0.f, 0.f};
      acc[mi][ni] = z;
    }

#pragma unroll
  for (int kh = 0; kh < 2; ++kh) {
    if (kh) __syncthreads();
#pragma unroll
    for (int i = 0; i < 4; ++i) {
      int idx = i * 256 + tid;
      int row = idx >> 3, c = idx & 7;
      *(uint4*)(As + row * LST + c * 8) =
          *(const uint4*)(Gb + (size_t)row * 128 + kh * 64 + c * 8);
      *(uint4*)(Bs + row * LST + c * 8) =
          *(const uint4*)(Pb + (size_t)row * 128 + kh * 64 + c * 8);
    }
    __syncthreads();

#pragma unroll
    for (int ks = 0; ks < 2; ++ks) {
      bh8 a[4], bf[4];
#pragma unroll
      for (int i = 0; i < 4; ++i) {
        a[i]  = *(const bh8*)(As + (wrow * 64 + i * 16 + lr) * LST + ks * 32 + kg * 8);
        bf[i] = *(const bh8*)(Bs + (wcol * 64 + i * 16 + lr) * LST + ks * 32 + kg * 8);
      }
#pragma unroll
      for (int mi = 0; mi < 4; ++mi)
#pragma unroll
        for (int ni = 0; ni < 4; ++ni)
          acc[mi][ni] = __builtin_amdgcn_mfma_f32_16x16x32_bf16(
              a[mi], bf[ni], acc[mi][ni], 0, 0, 0);
    }
  }

#pragma unroll
  for (int mi = 0; mi < 4; ++mi) {
    int lg = l0 + wrow * 64 + mi * 16 + kg * 4;
#pragma unroll
    for (int ni = 0; ni < 4; ++ni) {
      int e = e0 + wcol * 64 + ni * 16 + lr;
#pragma unroll
      for (int j = 0; j < 4; ++j)
        y[((size_t)b * L_ + (lg + j)) * D_ + e] = acc[mi][ni][j];
    }
  }
}

// --------------------------------------------------------------------- launcher
extern "C" void kernel_launch(void* const* d_in, const int* in_sizes, int n_in,
                              void* d_out, int out_size, void* d_ws, size_t ws_size,
                              hipStream_t stream) {
  const float* q  = (const float*)d_in[0];
  const float* wr = (const float*)d_in[1];
  const float* wi = (const float*)d_in[2];
  float* out = (float*)d_out;
  char* ws = (char*)d_ws;

  // ws: Fbf 1MB | Gbf 1MB | Qbf 1MB | Pw 1MB = 4 MB (<=10MB proven)
  unsigned short* Fbf = (unsigned short*)ws;
  unsigned short* Gbf = (unsigned short*)(ws + (1u << 20));
  unsigned* Qbf       = (unsigned*)(ws + (2u << 20));
  unsigned* Pw        = (unsigned*)(ws + (3u << 20));

  // d_out scratch phases (stream-ordered):
  //   k_dft_mfma -> pQ (16.8 MB), consumed by k_red2;
  //   k_mix_mfma -> pOut (33.5 MB), consumed by k_psum2;
  //   k_inv_mfma overwrites all 64 MB.
  float* pQ   = out;
  float* pOut = out;

  hipLaunchKernelGGL(k_ftab, dim3((128 * L_) / 256), dim3(256), 0, stream, Fbf);
  hipLaunchKernelGGL(k_gtab, dim3((L_ * 128) / 256), dim3(256), 0, stream, Gbf);
  hipLaunchKernelGGL(k_dft_mfma, dim3(8, 8, 8), dim3(512), 0, stream,
                     q, Fbf, pQ);
  hipLaunchKernelGGL(k_red2, dim3(65536 / 256), dim3(256), 0, stream, pQ, Qbf);
  hipLaunchKernelGGL(k_mix_mfma, dim3(32, 16, 4), dim3(256), 0, stream,
                     wr, wi, Qbf, pOut);
  hipLaunchKernelGGL(k_psum2, dim3(16, 8), dim3(256), 0, stream, pOut, Pw);
  hipLaunchKernelGGL(k_inv_mfma, dim3(L_ / 128, D_ / 128, B_), dim3(256), 0,
                     stream, (const short*)Gbf, (const short*)Pw, out);
}

// Round 16
// 111.767 us; speedup vs baseline: 1.0174x; 1.0174x over previous
//
#include <hip/hip_runtime.h>

#define B_ 8
#define L_ 4096
#define D_ 512
#define M_ 64

typedef __attribute__((ext_vector_type(8))) short bh8;
typedef __attribute__((ext_vector_type(4))) float f4;
typedef __attribute__((ext_vector_type(4))) unsigned u32x4;

__device__ inline unsigned short f2bf(float f) {
  unsigned u = __float_as_uint(f);
  return (unsigned short)((u + 0x7fffu + ((u >> 16) & 1u)) >> 16);
}
__device__ inline unsigned packbf(float lo, float hi) {
  return (unsigned)f2bf(lo) | ((unsigned)f2bf(hi) << 16);
}

// ---------------- forward-DFT coefficient matrix (bf16), PLAIN row-major [r][l]
__global__ void k_ftab(unsigned short* __restrict__ F) {
  int t = blockIdx.x * 256 + threadIdx.x;  // 128*4096
  int r = t >> 12, l = t & 4095;
  int k = r & 63, part = r >> 6;
  int ph = (k * l) & (L_ - 1);
  double ang = 6.283185307179586476925286766559 * (double)ph / (double)L_;
  float v = part ? (float)(-sin(ang)) : (float)(cos(ang));
  F[t] = f2bf(v);
}

// ----------------------------------------- inverse-DFT coefficient matrix (bf16)
__global__ void k_gtab(unsigned short* __restrict__ G) {
  int t = blockIdx.x * 256 + threadIdx.x;  // L_*128
  int l = t >> 7, j = t & 127;
  int k = j & 63, part = j >> 6;
  int ph = (k * l) & (L_ - 1);
  double ang = 6.283185307179586476925286766559 * (double)ph / (double)L_;
  double ck = (k == 0 ? 1.0 : 2.0) / (double)L_;
  float v = part ? (float)(-ck * sin(ang)) : (float)(ck * cos(ang));
  G[t] = f2bf(v);
}

// ------------------------- stage 1: Qft = F(128x4096) * q[b](4096x512) via MFMA
__global__ __launch_bounds__(512, 4) void k_dft_mfma(
    const float* __restrict__ q, const unsigned short* __restrict__ F,
    float* __restrict__ pQ) {
  int tid = threadIdx.x;
  int dt = blockIdx.x, b = blockIdx.y, kc = blockIdx.z;
  int d0 = dt * 64;
  int lbase = kc * 512;

  int w = tid >> 6, lane = tid & 63;
  int mh = w & 3, nc = w >> 2;
  int lr = lane & 15, kg = lane >> 4;

  f4 acc[2][2];
#pragma unroll
  for (int i = 0; i < 2; ++i)
#pragma unroll
    for (int j = 0; j < 2; ++j) { f4 z = {0.f, 0.f, 0.f, 0.f}; acc[i][j] = z; }

  const unsigned short* A0 = F + (size_t)(mh * 32 + lr) * 4096 + lbase + kg * 8;
  const unsigned short* A1 = A0 + (size_t)16 * 4096;
  const float* q0 = q + ((size_t)b * L_ + lbase + kg * 8) * D_ + d0 + nc * 32 + lr;

#pragma unroll 2
  for (int s = 0; s < 16; ++s) {
    const float* qs = q0 + (size_t)s * 32 * D_;
    float v0[8], v1[8];
#pragma unroll
    for (int j = 0; j < 8; ++j) {
      v0[j] = qs[(size_t)j * D_];
      v1[j] = qs[(size_t)j * D_ + 16];
    }
    union { u32x4 u; bh8 h; } bf0, bf1;
    bf0.u.x = packbf(v0[0], v0[1]); bf0.u.y = packbf(v0[2], v0[3]);
    bf0.u.z = packbf(v0[4], v0[5]); bf0.u.w = packbf(v0[6], v0[7]);
    bf1.u.x = packbf(v1[0], v1[1]); bf1.u.y = packbf(v1[2], v1[3]);
    bf1.u.z = packbf(v1[4], v1[5]); bf1.u.w = packbf(v1[6], v1[7]);
    bh8 af0 = *(const bh8*)(A0 + s * 32);
    bh8 af1 = *(const bh8*)(A1 + s * 32);
    acc[0][0] = __builtin_amdgcn_mfma_f32_16x16x32_bf16(af0, bf0.h, acc[0][0], 0, 0, 0);
    acc[0][1] = __builtin_amdgcn_mfma_f32_16x16x32_bf16(af0, bf1.h, acc[0][1], 0, 0, 0);
    acc[1][0] = __builtin_amdgcn_mfma_f32_16x16x32_bf16(af1, bf0.h, acc[1][0], 0, 0, 0);
    acc[1][1] = __builtin_amdgcn_mfma_f32_16x16x32_bf16(af1, bf1.h, acc[1][1], 0, 0, 0);
  }

#pragma unroll
  for (int mi = 0; mi < 2; ++mi) {
    int r = mh * 32 + mi * 16 + kg * 4;
#pragma unroll
    for (int ni = 0; ni < 2; ++ni) {
      int d = d0 + nc * 32 + ni * 16 + lr;
#pragma unroll
      for (int j = 0; j < 4; ++j)
        pQ[(((size_t)kc * 128 + (r + j)) * 8 + b) * 512 + d] = acc[mi][ni][j];
    }
  }
}

// -------------- reduce kc chunks + pack bf16 Qbf[k][b][d]: word = (Qr, Qi)
__global__ __launch_bounds__(256) void k_red2(const float* __restrict__ pQ,
                                              unsigned* __restrict__ Qbf) {
  int g = blockIdx.x * 256 + threadIdx.x;  // 64*8*128 = 65536
  int dq = g & 127;
  int b = (g >> 7) & 7;
  int k = g >> 10;
  f4 sr = {0.f, 0.f, 0.f, 0.f}, si = {0.f, 0.f, 0.f, 0.f};
#pragma unroll
  for (int kc = 0; kc < 8; ++kc) {
    size_t base = (((size_t)kc * 128 + k) * 8 + b) * 512 + dq * 4;
    sr += *(const f4*)(pQ + base);
    si += *(const f4*)(pQ + base + (size_t)64 * 8 * 512);
  }
  u32x4 o;
  o.x = packbf(sr[0], si[0]); o.y = packbf(sr[1], si[1]);
  o.z = packbf(sr[2], si[2]); o.w = packbf(sr[3], si[3]);
  *(u32x4*)(Qbf + ((size_t)k * 8 + b) * 512 + dq * 4) = o;
}

// ------------------------- stage 2 v11: barrier-free mode-mix, CORRECT LDS SIZE
// v10 with the overflow fixed: per-wave buffer [k16][e16][d16] = 4096 words =
// 16 KB (was 2048 = 8 KB -> waves clobbered each other, the v9/v10 failures).
// 64 KB total, 2 blocks/CU, zero s_barrier; DS fences retained.
__global__ __launch_bounds__(256, 2) void k_mix_mfma(
    const float* __restrict__ wr_, const float* __restrict__ wi_,
    const unsigned* __restrict__ Qbf, float* __restrict__ pOut) {
  __shared__ unsigned Wlds[4 * 4096];  // 64 KB, 16 KB per wave: [k16][e16][d16]

  int tid = threadIdx.x;
  int et = blockIdx.x, dc = blockIdx.y, kh = blockIdx.z;
  int e0 = et * 16;
  int w = tid >> 6, lane = tid & 63;
  int er = lane & 15, kg = lane >> 4;
  int part = er >> 3, b = er & 7;
  int dh = w & 1;
  int ksl = kh * 32 + (w >> 1) * 16;  // global k base of this wave's 16 k
  unsigned* wbuf = Wlds + w * 4096;

  // load-phase lane roles
  int dL = lane >> 4;        // 0-3
  int eL = (lane >> 2) & 3;  // 0-3
  int kq = lane & 3;         // 0-3

  f4 acc[16];
#pragma unroll
  for (int t = 0; t < 16; ++t) { f4 z = {0.f, 0.f, 0.f, 0.f}; acc[t] = z; }

  const unsigned* qbase = Qbf + ((size_t)ksl * 8 + b) * 512 + kg * 4;

#define DSFENCE() do {                                        \
    asm volatile("s_waitcnt lgkmcnt(0)" ::: "memory");        \
    __builtin_amdgcn_sched_barrier(0);                        \
  } while (0)

#pragma unroll 1
  for (int r = 0; r < 2; ++r) {
    int dbase = dc * 64 + r * 32 + dh * 16;

    // ---- stage the wave's (d16, e16, k16) tile, two 8-d sub-batches
#pragma unroll 1
    for (int s = 0; s < 2; ++s) {
      float4 vr[8], vi[8];
#pragma unroll
      for (int i = 0; i < 8; ++i) {
        int d = dbase + s * 8 + dL + (i & 1) * 4;
        int e = e0 + eL + (i >> 1) * 4;
        size_t gb = ((size_t)d * 512 + e) * 64 + ksl + kq * 4;
        vr[i] = *(const float4*)(wr_ + gb);
        vi[i] = *(const float4*)(wi_ + gb);
      }
#pragma unroll
      for (int i = 0; i < 8; ++i) {
        int ee = eL + (i >> 1) * 4;
        int dd = s * 8 + dL + (i & 1) * 4;
        int ddp = dd ^ (kq << 2);            // bank swizzle (involution)
        unsigned* o = wbuf + ee * 16 + ddp;  // + kk*256 below
        o[(kq * 4 + 0) * 256] = packbf(vr[i].x, vi[i].x);
        o[(kq * 4 + 1) * 256] = packbf(vr[i].y, vi[i].y);
        o[(kq * 4 + 2) * 256] = packbf(vr[i].z, vi[i].z);
        o[(kq * 4 + 3) * 256] = packbf(vr[i].w, vi[i].w);
      }
    }
    DSFENCE();  // all pack-writes complete before any consume-read issues

    // ---- consume: 16 k, one MFMA each (A = W from private LDS, B = Q+sign/rot)
#pragma unroll
    for (int kl = 0; kl < 16; ++kl) {
      union { u32x4 u; bh8 h; } av, bv;
      av.u = *(const u32x4*)(wbuf + kl * 256 + er * 16 + ((kg ^ (kl >> 2)) << 2));
      u32x4 qv = *(const u32x4*)(qbase + (size_t)kl * 4096 + dbase);
      if (part == 0) {
        bv.u.x = qv.x ^ 0x80000000u; bv.u.y = qv.y ^ 0x80000000u;
        bv.u.z = qv.z ^ 0x80000000u; bv.u.w = qv.w ^ 0x80000000u;
      } else {
        bv.u.x = (qv.x >> 16) | (qv.x << 16); bv.u.y = (qv.y >> 16) | (qv.y << 16);
        bv.u.z = (qv.z >> 16) | (qv.z << 16); bv.u.w = (qv.w >> 16) | (qv.w << 16);
      }
      acc[kl] = __builtin_amdgcn_mfma_f32_16x16x32_bf16(av.h, bv.h, acc[kl], 0, 0, 0);
    }
    DSFENCE();  // all consume-reads complete before next round's writes
  }
#undef DSFENCE

  // epilogue: pOut[chunk = dc*2+dh][(kglob*2+part)*8+b][e512]
#pragma unroll
  for (int kl = 0; kl < 16; ++kl) {
    int kglob = ksl + kl;
    size_t off = (size_t)(dc * 2 + dh) * 524288 +
                 (((size_t)kglob * 2 + part) * 8 + b) * 512 + e0 + kg * 4;
    *(f4*)(pOut + off) = acc[kl];
  }
}

// ------------- reduce pOut over 16 chunks + transpose to bf16 P[b][e][part*64+k]
__global__ __launch_bounds__(256) void k_psum2(const float* __restrict__ pOut,
                                               unsigned* __restrict__ Pw) {
  __shared__ float sP[128 * 33];
  int tid = threadIdx.x;
  int e0 = blockIdx.x * 32, b = blockIdx.y;
  {
    int e = tid & 31, kg4 = tid >> 5;
#pragma unroll
    for (int ii = 0; ii < 16; ++ii) {
      int col = kg4 * 16 + ii;
      int rkp = ((col & 63) << 1) | (col >> 6);
      float s = 0.f;
#pragma unroll
      for (int c = 0; c < 16; ++c)
        s += pOut[(size_t)c * 524288 + (size_t)rkp * 4096 + b * 512 + e0 + e];
      sP[col * 33 + e] = s;
    }
  }
  __syncthreads();
  {
    int e = tid >> 3, c = tid & 7;
    size_t wbase = (((size_t)b * 512 + e0 + e) * 128 + c * 16) >> 1;
#pragma unroll
    for (int ii = 0; ii < 8; ++ii) {
      int col = c * 16 + ii * 2;
      Pw[wbase + ii] = packbf(sP[col * 33 + e], sP[(col + 1) * 33 + e]);
    }
  }
}

// ------------------------- stage 3: y[b] = G(4096x128) * P[b](512x128)^T via MFMA
#define LST 72
__global__ __launch_bounds__(256, 2) void k_inv_mfma(
    const short* __restrict__ G, const short* __restrict__ P,
    float* __restrict__ y) {
  __shared__ short lds[2 * 128 * LST];
  short* As = lds;
  short* Bs = lds + 128 * LST;

  int tid = threadIdx.x;
  int lt = blockIdx.x, et = blockIdx.y, b = blockIdx.z;
  int l0 = lt * 128, e0 = et * 128;

  int wv = tid >> 6, lane = tid & 63;
  int wrow = wv >> 1, wcol = wv & 1;
  int lr = lane & 15, kg = lane >> 4;

  const short* Gb = G + (size_t)l0 * 128;
  const short* Pb = P + (size_t)b * D_ * 128 + (size_t)e0 * 128;

  f4 acc[4][4];
#pragma unroll
  for (int mi = 0; mi < 4; ++mi)
#pragma unroll
    for (int ni = 0; ni < 4; ++ni) {
      f4 z = {0.f, 0.f, 0.f, 0.f};
      acc[mi][ni] = z;
    }

#pragma unroll
  for (int kh = 0; kh < 2; ++kh) {
    if (kh) __syncthreads();
#pragma unroll
    for (int i = 0; i < 4; ++i) {
      int idx = i * 256 + tid;
      int row = idx >> 3, c = idx & 7;
      *(uint4*)(As + row * LST + c * 8) =
          *(const uint4*)(Gb + (size_t)row * 128 + kh * 64 + c * 8);
      *(uint4*)(Bs + row * LST + c * 8) =
          *(const uint4*)(Pb + (size_t)row * 128 + kh * 64 + c * 8);
    }
    __syncthreads();

#pragma unroll
    for (int ks = 0; ks < 2; ++ks) {
      bh8 a[4], bf[4];
#pragma unroll
      for (int i = 0; i < 4; ++i) {
        a[i]  = *(const bh8*)(As + (wrow * 64 + i * 16 + lr) * LST + ks * 32 + kg * 8);
        bf[i] = *(const bh8*)(Bs + (wcol * 64 + i * 16 + lr) * LST + ks * 32 + kg * 8);
      }
#pragma unroll
      for (int mi = 0; mi < 4; ++mi)
#pragma unroll
        for (int ni = 0; ni < 4; ++ni)
          acc[mi][ni] = __builtin_amdgcn_mfma_f32_16x16x32_bf16(
              a[mi], bf[ni], acc[mi][ni], 0, 0, 0);
    }
  }

#pragma unroll
  for (int mi = 0; mi < 4; ++mi) {
    int lg = l0 + wrow * 64 + mi * 16 + kg * 4;
#pragma unroll
    for (int ni = 0; ni < 4; ++ni) {
      int e = e0 + wcol * 64 + ni * 16 + lr;
#pragma unroll
      for (int j = 0; j < 4; ++j)
        y[((size_t)b * L_ + (lg + j)) * D_ + e] = acc[mi][ni][j];
    }
  }
}

// --------------------------------------------------------------------- launcher
extern "C" void kernel_launch(void* const* d_in, const int* in_sizes, int n_in,
                              void* d_out, int out_size, void* d_ws, size_t ws_size,
                              hipStream_t stream) {
  const float* q  = (const float*)d_in[0];
  const float* wr = (const float*)d_in[1];
  const float* wi = (const float*)d_in[2];
  float* out = (float*)d_out;
  char* ws = (char*)d_ws;

  // ws: Fbf 1MB | Gbf 1MB | Qbf 1MB | Pw 1MB = 4 MB (<=10MB proven)
  unsigned short* Fbf = (unsigned short*)ws;
  unsigned short* Gbf = (unsigned short*)(ws + (1u << 20));
  unsigned* Qbf       = (unsigned*)(ws + (2u << 20));
  unsigned* Pw        = (unsigned*)(ws + (3u << 20));

  // d_out scratch phases (stream-ordered):
  //   k_dft_mfma -> pQ (16.8 MB), consumed by k_red2;
  //   k_mix_mfma -> pOut (33.5 MB), consumed by k_psum2;
  //   k_inv_mfma overwrites all 64 MB.
  float* pQ   = out;
  float* pOut = out;

  hipLaunchKernelGGL(k_ftab, dim3((128 * L_) / 256), dim3(256), 0, stream, Fbf);
  hipLaunchKernelGGL(k_gtab, dim3((L_ * 128) / 256), dim3(256), 0, stream, Gbf);
  hipLaunchKernelGGL(k_dft_mfma, dim3(8, 8, 8), dim3(512), 0, stream,
                     q, Fbf, pQ);
  hipLaunchKernelGGL(k_red2, dim3(65536 / 256), dim3(256), 0, stream, pQ, Qbf);
  hipLaunchKernelGGL(k_mix_mfma, dim3(32, 8, 2), dim3(256), 0, stream,
                     wr, wi, Qbf, pOut);
  hipLaunchKernelGGL(k_psum2, dim3(16, 8), dim3(256), 0, stream, pOut, Pw);
  hipLaunchKernelGGL(k_inv_mfma, dim3(L_ / 128, D_ / 128, B_), dim3(256), 0,
                     stream, (const short*)Gbf, (const short*)Pw, out);
}